// Round 8
// baseline (434.684 us; speedup 1.0000x reference)
//
#include <hip/hip_runtime.h>

typedef __bf16 bf16x8 __attribute__((ext_vector_type(8)));
typedef __bf16 bf16x4 __attribute__((ext_vector_type(4)));
typedef float f32x4 __attribute__((ext_vector_type(4)));
typedef float f32x16 __attribute__((ext_vector_type(16)));
typedef unsigned short u16x8 __attribute__((ext_vector_type(8)));
typedef unsigned short u16x4 __attribute__((ext_vector_type(4)));
typedef unsigned int u32x4 __attribute__((ext_vector_type(4)));
typedef unsigned short us;

#define MM 2048
#define TT 4096

__device__ __forceinline__ us f2bf(float f){
  unsigned int u = __builtin_bit_cast(unsigned int, f);
  u = (u + 0x7fffu + ((u >> 16) & 1u)) >> 16;
  return (us)u;
}
__device__ __forceinline__ float bf2f(us u){
  unsigned int x = ((unsigned int)u) << 16;
  return __builtin_bit_cast(float, x);
}
__device__ __forceinline__ unsigned int cvt_pk_bf16(float lo, float hi){
  unsigned int r;
  asm("v_cvt_pk_bf16_f32 %0, %1, %2" : "=v"(r) : "v"(lo), "v"(hi));
  return r;
}
__device__ __forceinline__ void plane_swap(unsigned int &x, unsigned int &y){
  asm("v_permlane32_swap_b32 %0, %1" : "+v"(x), "+v"(y));
}

#define GLDS(gp, lp) __builtin_amdgcn_global_load_lds( \
    (const __attribute__((address_space(1))) unsigned int*)(gp), \
    (__attribute__((address_space(3))) unsigned int*)(lp), 16, 0, 0)

// ---------------- fused fp32 -> bf16 hi/lo split (x and data in one launch) ----------------
__global__ __launch_bounds__(256) void split_cast_all(const float* __restrict__ x,
                                                      const float* __restrict__ data,
                                                      us* __restrict__ xh, us* __restrict__ xl,
                                                      us* __restrict__ dh, us* __restrict__ dl){
  int bid = blockIdx.x;
  const float* in; us* ho; us* lo;
  if (bid < 2048){ in = x; ho = xh; lo = xl; }
  else           { in = data; ho = dh; lo = dl; bid -= 2048; }
  size_t i = ((size_t)bid * 256 + threadIdx.x) * 8;
  float4 a = *(const float4*)(in + i);
  float4 b = *(const float4*)(in + i + 4);
  float v[8] = {a.x,a.y,a.z,a.w,b.x,b.y,b.z,b.w};
  u16x8 rh, rl;
  for (int j = 0; j < 8; j++){
    us h = f2bf(v[j]);
    rh[j] = h;
    rl[j] = f2bf(v[j] - bf2f(h));
  }
  *(u16x8*)(ho + i) = rh;
  *(u16x8*)(lo + i) = rl;
}

// ---------------- fused transpose + split for all three weights ----------------
__global__ __launch_bounds__(256) void transpose_all(const float* __restrict__ W_attn,
                                                     const float* __restrict__ W_data,
                                                     const float* __restrict__ W_proj,
                                                     us* __restrict__ Ah, us* __restrict__ Al,
                                                     us* __restrict__ Dh, us* __restrict__ Dl,
                                                     us* __restrict__ Ph, us* __restrict__ Pl2){
  __shared__ float tile[32][33];
  int bx = blockIdx.x;
  const float* W; us* oh; us* ol; int N;
  if (bx < 96){ W = W_attn; oh = Ah; ol = Al; N = 3072; }
  else if (bx < 160){ W = W_data; oh = Dh; ol = Dl; N = 2048; bx -= 96; }
  else { W = W_proj; oh = Ph; ol = Pl2; N = 1024; bx -= 160; }
  int tx = threadIdx.x & 31, ty = threadIdx.x >> 5;   // 32 x 8
  int n0 = bx * 32, k0 = blockIdx.y * 32;
  for (int r = 0; r < 32; r += 8)
    tile[ty + r][tx] = W[(size_t)(k0 + ty + r) * N + n0 + tx];
  __syncthreads();
  for (int r = 0; r < 32; r += 8){
    float v = tile[tx][ty + r];
    us h = f2bf(v);
    size_t idx = (size_t)(n0 + ty + r) * 1024 + k0 + tx;
    oh[idx] = h;
    ol[idx] = f2bf(v - bf2f(h));
  }
}

// ---------------- merged projection GEMM (q/k/v and k_data/v_data in one launch) ----------------
// bx<24: x @ W_attn (regions 0,1,2: Q,K,V, kroff 0). bx>=24: data @ W_data (regions 1,2, kroff 2048).
// 128x128 tile, BK=32, 4 waves (2x2), 16x16x32 MFMA. Split regions use 3-MFMA hi/lo emulation.
__global__ __launch_bounds__(256) void gemm_all(const us* __restrict__ xb_hi, const us* __restrict__ xb_lo,
                                                const us* __restrict__ db_hi, const us* __restrict__ db_lo,
                                                const us* __restrict__ Wat_hi, const us* __restrict__ Wat_lo,
                                                const us* __restrict__ Wdt_hi, const us* __restrict__ Wdt_lo,
                                                const float* __restrict__ b_attn, const float* __restrict__ b_data,
                                                us* __restrict__ Qh, us* __restrict__ Ql,
                                                us* __restrict__ Kh, us* __restrict__ Kl,
                                                us* __restrict__ VT){
  __shared__ us sm[16384];  // Ah@0, Bh@4096, Al@8192, Bl@12288
  const int bx = blockIdx.x;
  const us *Ah, *Al, *Bth, *Btl; const float* bias; int region, kroff, col0;
  if (bx < 24){
    Ah = xb_hi; Al = xb_lo; Bth = Wat_hi; Btl = Wat_lo; bias = b_attn;
    region = bx >> 3; kroff = 0; col0 = bx * 128;
  } else {
    int b2 = bx - 24;
    Ah = db_hi; Al = db_lo; Bth = Wdt_hi; Btl = Wdt_lo; bias = b_data;
    region = 1 + (b2 >> 3); kroff = 2048; col0 = b2 * 128;
  }
  const bool split = (region < 2);
  const int tid = threadIdx.x, wid = tid >> 6, lane = tid & 63;
  const int l15 = lane & 15, l16 = lane >> 4;
  const int row0 = blockIdx.y * 128;
  const int wr = (wid >> 1) * 64, wc = (wid & 1) * 64;
  f32x4 acc[4][4] = {};

  for (int k0 = 0; k0 < 1024; k0 += 32){
    for (int c = 0; c < 2; ++c){
      int i = c * 256 + tid;                           // 0..511: row=i>>2, k8=(i&3)*8
      size_t aoff = (size_t)(row0 + (i >> 2)) * 1024 + k0 + (i & 3) * 8;
      size_t boff = (size_t)(col0 + (i >> 2)) * 1024 + k0 + (i & 3) * 8;
      GLDS(Ah + aoff, &sm[c * 2048 + wid * 512]);
      GLDS(Bth + boff, &sm[4096 + c * 2048 + wid * 512]);
      if (split){
        GLDS(Al + aoff, &sm[8192 + c * 2048 + wid * 512]);
        GLDS(Btl + boff, &sm[12288 + c * 2048 + wid * 512]);
      }
    }
    __syncthreads();
    bf16x8 afh[4], bfh[4];
    for (int m = 0; m < 4; m++) afh[m] = *(const bf16x8*)&sm[(wr + m * 16 + l15) * 32 + l16 * 8];
    for (int n = 0; n < 4; n++) bfh[n] = *(const bf16x8*)&sm[4096 + (wc + n * 16 + l15) * 32 + l16 * 8];
    if (split){
      bf16x8 afl[4], bfl[4];
      for (int m = 0; m < 4; m++) afl[m] = *(const bf16x8*)&sm[8192 + (wr + m * 16 + l15) * 32 + l16 * 8];
      for (int n = 0; n < 4; n++) bfl[n] = *(const bf16x8*)&sm[12288 + (wc + n * 16 + l15) * 32 + l16 * 8];
      for (int m = 0; m < 4; m++)
        for (int n = 0; n < 4; n++){
          acc[m][n] = __builtin_amdgcn_mfma_f32_16x16x32_bf16(afh[m], bfh[n], acc[m][n], 0, 0, 0);
          acc[m][n] = __builtin_amdgcn_mfma_f32_16x16x32_bf16(afh[m], bfl[n], acc[m][n], 0, 0, 0);
          acc[m][n] = __builtin_amdgcn_mfma_f32_16x16x32_bf16(afl[m], bfh[n], acc[m][n], 0, 0, 0);
        }
    } else {
      for (int m = 0; m < 4; m++)
        for (int n = 0; n < 4; n++)
          acc[m][n] = __builtin_amdgcn_mfma_f32_16x16x32_bf16(afh[m], bfh[n], acc[m][n], 0, 0, 0);
    }
    __syncthreads();
  }

  for (int m = 0; m < 4; m++)
    for (int n = 0; n < 4; n++){
      int gcol = col0 + wc + n * 16 + l15;
      int ocol = gcol & 1023;
      float bv = bias[gcol];
      if (region == 2){                    // V -> VT[b][d][t], vectorized over 4 rows
        int r = row0 + wr + m * 16 + l16 * 4;
        u16x4 o;
        for (int j = 0; j < 4; j++) o[j] = f2bf(acc[m][n][j] + bv);
        *(u16x4*)&VT[((size_t)((r >> 11) * 1024 + ocol)) * 4096 + kroff + (r & 2047)] = o;
      } else {
        us* Ph = (region == 0) ? Qh : Kh;
        us* Pllo = (region == 0) ? Ql : Kl;
        for (int j = 0; j < 4; j++){
          int r = row0 + wr + m * 16 + l16 * 4 + j;
          size_t orow = (region == 0) ? (size_t)r
                                      : (size_t)((r >> 11) * 4096 + kroff + (r & 2047));
          float v = acc[m][n][j] + bv;
          us h = f2bf(v);
          Ph[orow * 1024 + ocol] = h;
          Pllo[orow * 1024 + ocol] = f2bf(v - bf2f(h));
        }
      }
    }
}

// ---------------- output projection GEMM (plain, fp32 out) ----------------
__global__ __launch_bounds__(256) void gemm_proj(const us* __restrict__ Ah,
                                                 const us* __restrict__ Bth,
                                                 const float* __restrict__ bias,
                                                 float* __restrict__ Co){
  __shared__ us sm[8192];
  const int tid = threadIdx.x, wid = tid >> 6, lane = tid & 63;
  const int l15 = lane & 15, l16 = lane >> 4;
  const int row0 = blockIdx.y * 128, col0 = blockIdx.x * 128;
  const int wr = (wid >> 1) * 64, wc = (wid & 1) * 64;
  f32x4 acc[4][4] = {};

  for (int k0 = 0; k0 < 1024; k0 += 32){
    for (int c = 0; c < 2; ++c){
      int i = c * 256 + tid;
      size_t aoff = (size_t)(row0 + (i >> 2)) * 1024 + k0 + (i & 3) * 8;
      size_t boff = (size_t)(col0 + (i >> 2)) * 1024 + k0 + (i & 3) * 8;
      GLDS(Ah + aoff, &sm[c * 2048 + wid * 512]);
      GLDS(Bth + boff, &sm[4096 + c * 2048 + wid * 512]);
    }
    __syncthreads();
    bf16x8 afh[4], bfh[4];
    for (int m = 0; m < 4; m++) afh[m] = *(const bf16x8*)&sm[(wr + m * 16 + l15) * 32 + l16 * 8];
    for (int n = 0; n < 4; n++) bfh[n] = *(const bf16x8*)&sm[4096 + (wc + n * 16 + l15) * 32 + l16 * 8];
    for (int m = 0; m < 4; m++)
      for (int n = 0; n < 4; n++)
        acc[m][n] = __builtin_amdgcn_mfma_f32_16x16x32_bf16(afh[m], bfh[n], acc[m][n], 0, 0, 0);
    __syncthreads();
  }

  for (int m = 0; m < 4; m++)
    for (int n = 0; n < 4; n++){
      int col = col0 + wc + n * 16 + l15;
      float bv = bias[col];
      for (int j = 0; j < 4; j++){
        int r = row0 + wr + m * 16 + l16 * 4 + j;
        Co[(size_t)r * 1024 + col] = acc[m][n][j] + bv;
      }
    }
}

// ---------------- fused attention, split-T: grid = 2 T-chunks x B*H*(M/128) ----------------
// 4 waves x 32 q-rows; q = lane&31, hb = lane>>5. Each block sweeps 2048 t (32 tiles of 64).
// K,V single-buffered LDS (27.6 KB -> 4 blocks/CU), 2 barriers/tile, register prefetch.
// Writes UNNORMALIZED partial O (bf16) + per-(q,h) running max m (log2 domain) and sum l.
__global__ __launch_bounds__(256, 4) void attn_kernel(const us* __restrict__ Qh, const us* __restrict__ Ql,
                                                      const us* __restrict__ Kh, const us* __restrict__ Kl,
                                                      const us* __restrict__ VT,
                                                      us* __restrict__ accP,
                                                      float* __restrict__ Mv, float* __restrict__ Lv){
  __shared__ us KbH[64 * 72];
  __shared__ us KbL[64 * 72];
  __shared__ us Vb[64 * 72];
  const int tid = threadIdx.x, wid = tid >> 6, lane = tid & 63;
  const int l31 = lane & 31, hb = lane >> 5, h8 = hb * 8;
  const int qt = blockIdx.x & 15;             // M/128 = 16
  const int bh = (blockIdx.x >> 4) & 31;
  const int tch = blockIdx.x >> 9;            // T-chunk 0/1
  const int hd = (bh & 15) * 64, b = bh >> 4;
  const int qrow = qt * 128 + wid * 32 + l31;
  const int tbase = tch * 2048, tend = tbase + 2048;

  // Q fragments (B operand): lane holds Q[qrow][d = kk*16 + h8 + i]
  bf16x8 qfh[4], qfl[4];
  {
    const us* qp = Qh + (size_t)(b * MM + qrow) * 1024 + hd;
    const us* qq = Ql + (size_t)(b * MM + qrow) * 1024 + hd;
#pragma unroll
    for (int kk = 0; kk < 4; kk++){
      qfh[kk] = *(const bf16x8*)(qp + kk * 16 + h8);
      qfl[kk] = *(const bf16x8*)(qq + kk * 16 + h8);
    }
  }

  const int i0 = tid, i1 = 256 + tid;
  const int kt0 = i0 >> 3, kd0 = (i0 & 7) * 8;
  const int kt1 = i1 >> 3, kd1 = (i1 & 7) * 8;

#define GK(t0_, t_, d_) (((size_t)(b * TT + (t0_) + (t_))) * 1024 + hd + (d_))
#define GV(t0_, d_, t_) (((size_t)b * 1024 + hd + (d_)) * 4096 + (t0_) + (t_))

  // prologue: stage tile tbase
  uint4 rKh0 = *(const uint4*)(Kh + GK(tbase, kt0, kd0));
  uint4 rKh1 = *(const uint4*)(Kh + GK(tbase, kt1, kd1));
  uint4 rKl0 = *(const uint4*)(Kl + GK(tbase, kt0, kd0));
  uint4 rKl1 = *(const uint4*)(Kl + GK(tbase, kt1, kd1));
  uint4 rV0  = *(const uint4*)(VT + GV(tbase, kt0, kd0));
  uint4 rV1  = *(const uint4*)(VT + GV(tbase, kt1, kd1));
  *(uint4*)&KbH[kt0 * 72 + kd0] = rKh0;
  *(uint4*)&KbH[kt1 * 72 + kd1] = rKh1;
  *(uint4*)&KbL[kt0 * 72 + kd0] = rKl0;
  *(uint4*)&KbL[kt1 * 72 + kd1] = rKl1;
  *(uint4*)&Vb[kt0 * 72 + kd0] = rV0;
  *(uint4*)&Vb[kt1 * 72 + kd1] = rV1;
  __syncthreads();

  f32x16 acc0 = {}, acc1 = {};
  float mrow = -1e30f, lrow = 0.f;
  const float cs = 0.125f * 1.44269504088896f;   // to log2 domain

  for (int t0 = tbase; t0 < tend; t0 += 64){
    const bool pre = (t0 + 64 < tend);
    if (pre){
      rKh0 = *(const uint4*)(Kh + GK(t0 + 64, kt0, kd0));
      rKh1 = *(const uint4*)(Kh + GK(t0 + 64, kt1, kd1));
      rKl0 = *(const uint4*)(Kl + GK(t0 + 64, kt0, kd0));
      rKl1 = *(const uint4*)(Kl + GK(t0 + 64, kt1, kd1));
      rV0  = *(const uint4*)(VT + GV(t0 + 64, kt0, kd0));
      rV1  = *(const uint4*)(VT + GV(t0 + 64, kt1, kd1));
    }

    // S^T = K . Q^T (split): frag ts holds t = ts*32 + tloc, q = l31
    f32x16 sfr0 = {}, sfr1 = {};
    __builtin_amdgcn_s_setprio(1);
#pragma unroll
    for (int kk = 0; kk < 4; kk++){
      bf16x8 a0h = *(const bf16x8*)&KbH[l31 * 72 + kk * 16 + h8];
      bf16x8 a0l = *(const bf16x8*)&KbL[l31 * 72 + kk * 16 + h8];
      bf16x8 a1h = *(const bf16x8*)&KbH[(32 + l31) * 72 + kk * 16 + h8];
      bf16x8 a1l = *(const bf16x8*)&KbL[(32 + l31) * 72 + kk * 16 + h8];
      sfr0 = __builtin_amdgcn_mfma_f32_32x32x16_bf16(a0h, qfh[kk], sfr0, 0, 0, 0);
      sfr0 = __builtin_amdgcn_mfma_f32_32x32x16_bf16(a0l, qfh[kk], sfr0, 0, 0, 0);
      sfr0 = __builtin_amdgcn_mfma_f32_32x32x16_bf16(a0h, qfl[kk], sfr0, 0, 0, 0);
      sfr1 = __builtin_amdgcn_mfma_f32_32x32x16_bf16(a1h, qfh[kk], sfr1, 0, 0, 0);
      sfr1 = __builtin_amdgcn_mfma_f32_32x32x16_bf16(a1l, qfh[kk], sfr1, 0, 0, 0);
      sfr1 = __builtin_amdgcn_mfma_f32_32x32x16_bf16(a1h, qfl[kk], sfr1, 0, 0, 0);
    }
    __builtin_amdgcn_s_setprio(0);

    // online softmax (log2 domain, T13 defer-max, exp2 arg via fma fold)
    float v = -1e30f;
#pragma unroll
    for (int r = 0; r < 16; r++) v = fmaxf(v, fmaxf(sfr0[r], sfr1[r]));
    float vs = v * cs;
    vs = fmaxf(vs, __shfl_xor(vs, 32, 64));
    if (!__all(vs <= mrow + 8.f)){
      float mn = fmaxf(mrow, vs);
      float rs = __builtin_amdgcn_exp2f(mrow - mn);
      mrow = mn;
      lrow *= rs;
#pragma unroll
      for (int r = 0; r < 16; r++){ acc0[r] *= rs; acc1[r] *= rs; }
    }
    const float nm = -mrow;
    float tsum = 0.f;
    unsigned int A0[4][2], A1[4][2];
#pragma unroll
    for (int g = 0; g < 4; g++){
      float e00 = __builtin_amdgcn_exp2f(__builtin_fmaf(sfr0[4*g+0], cs, nm));
      float e01 = __builtin_amdgcn_exp2f(__builtin_fmaf(sfr0[4*g+1], cs, nm));
      float e02 = __builtin_amdgcn_exp2f(__builtin_fmaf(sfr0[4*g+2], cs, nm));
      float e03 = __builtin_amdgcn_exp2f(__builtin_fmaf(sfr0[4*g+3], cs, nm));
      float e10 = __builtin_amdgcn_exp2f(__builtin_fmaf(sfr1[4*g+0], cs, nm));
      float e11 = __builtin_amdgcn_exp2f(__builtin_fmaf(sfr1[4*g+1], cs, nm));
      float e12 = __builtin_amdgcn_exp2f(__builtin_fmaf(sfr1[4*g+2], cs, nm));
      float e13 = __builtin_amdgcn_exp2f(__builtin_fmaf(sfr1[4*g+3], cs, nm));
      tsum += (e00 + e01) + (e02 + e03) + (e10 + e11) + (e12 + e13);
      A0[g][0] = cvt_pk_bf16(e00, e01);
      A0[g][1] = cvt_pk_bf16(e02, e03);
      A1[g][0] = cvt_pk_bf16(e10, e11);
      A1[g][1] = cvt_pk_bf16(e12, e13);
    }
    tsum += __shfl_xor(tsum, 32, 64);
    lrow += tsum;

    // build P fragments in-register (T12): frag kk = {x'0, x'1, y'0, y'1}
    bf16x8 pf[4];
#pragma unroll
    for (int kkl = 0; kkl < 2; kkl++){
      unsigned int x0 = A0[2*kkl][0], y0 = A0[2*kkl+1][0];
      unsigned int x1 = A0[2*kkl][1], y1 = A0[2*kkl+1][1];
      plane_swap(x0, y0);
      plane_swap(x1, y1);
      u32x4 w = {x0, x1, y0, y1};
      pf[kkl] = __builtin_bit_cast(bf16x8, w);
      unsigned int z0 = A1[2*kkl][0], t0w = A1[2*kkl+1][0];
      unsigned int z1 = A1[2*kkl][1], t1w = A1[2*kkl+1][1];
      plane_swap(z0, t0w);
      plane_swap(z1, t1w);
      u32x4 w2 = {z0, z1, t0w, t1w};
      pf[2 + kkl] = __builtin_bit_cast(bf16x8, w2);
    }

    // O^T += V^T . P^T : A = V^T rows (LDS, shared), B = P (in-register)
    __builtin_amdgcn_s_setprio(1);
#pragma unroll
    for (int kk = 0; kk < 4; kk++){
      bf16x8 av0 = *(const bf16x8*)&Vb[l31 * 72 + kk * 16 + h8];
      bf16x8 av1 = *(const bf16x8*)&Vb[(32 + l31) * 72 + kk * 16 + h8];
      acc0 = __builtin_amdgcn_mfma_f32_32x32x16_bf16(av0, pf[kk], acc0, 0, 0, 0);
      acc1 = __builtin_amdgcn_mfma_f32_32x32x16_bf16(av1, pf[kk], acc1, 0, 0, 0);
    }
    __builtin_amdgcn_s_setprio(0);

    __syncthreads();             // all waves done reading K/V LDS of this tile
    if (pre){
      *(uint4*)&KbH[kt0 * 72 + kd0] = rKh0;
      *(uint4*)&KbH[kt1 * 72 + kd1] = rKh1;
      *(uint4*)&KbL[kt0 * 72 + kd0] = rKl0;
      *(uint4*)&KbL[kt1 * 72 + kd1] = rKl1;
      *(uint4*)&Vb[kt0 * 72 + kd0] = rV0;
      *(uint4*)&Vb[kt1 * 72 + kd1] = rV1;
    }
    __syncthreads();             // writes visible before next tile
  }
#undef GK
#undef GV

  // unnormalized partial output + m/l scalars
  us* ap = accP + (size_t)tch * 4194304 + (size_t)(b * MM + qrow) * 1024 + hd;
#pragma unroll
  for (int g = 0; g < 4; g++){
    bf16x4 w0, w1;
#pragma unroll
    for (int j = 0; j < 4; j++){
      w0[j] = (__bf16)acc0[4 * g + j];
      w1[j] = (__bf16)acc1[4 * g + j];
    }
    *(u16x4*)&ap[8 * g + 4 * hb]      = __builtin_bit_cast(u16x4, w0);
    *(u16x4*)&ap[32 + 8 * g + 4 * hb] = __builtin_bit_cast(u16x4, w1);
  }
  if (hb == 0){
    int idx = tch * 65536 + (b * MM + qrow) * 16 + (hd >> 6);
    Mv[idx] = mrow;
    Lv[idx] = lrow;
  }
}

// ---------------- combine the two T-chunk partials ----------------
__global__ __launch_bounds__(256) void combine_kernel(const us* __restrict__ accP,
                                                      const float* __restrict__ Mv,
                                                      const float* __restrict__ Lv,
                                                      us* __restrict__ attno){
  size_t i = ((size_t)blockIdx.x * 256 + threadIdx.x) * 8;
  size_t qg = i >> 10;
  int h = (int)((i & 1023) >> 6);
  size_t mi = qg * 16 + h;
  float m1 = Mv[mi], m2 = Mv[65536 + mi];
  float l1 = Lv[mi], l2 = Lv[65536 + mi];
  float m = fmaxf(m1, m2);
  float w1 = __builtin_amdgcn_exp2f(m1 - m);
  float w2 = __builtin_amdgcn_exp2f(m2 - m);
  float inv = 1.f / (w1 * l1 + w2 * l2);
  float s1 = w1 * inv, s2 = w2 * inv;
  u16x8 a1 = *(const u16x8*)(accP + i);
  u16x8 a2 = *(const u16x8*)(accP + 4194304 + i);
  u16x8 o;
#pragma unroll
  for (int j = 0; j < 8; j++)
    o[j] = f2bf(s1 * bf2f(a1[j]) + s2 * bf2f(a2[j]));
  *(u16x8*)(attno + i) = o;
}

extern "C" void kernel_launch(void* const* d_in, const int* in_sizes, int n_in,
                              void* d_out, int out_size, void* d_ws, size_t ws_size,
                              hipStream_t stream){
  const float* x      = (const float*)d_in[0];
  const float* data   = (const float*)d_in[1];
  const float* W_attn = (const float*)d_in[2];
  const float* b_attn = (const float*)d_in[3];
  const float* W_data = (const float*)d_in[4];
  const float* b_data = (const float*)d_in[5];
  const float* W_proj = (const float*)d_in[6];
  const float* b_proj = (const float*)d_in[7];
  float* out = (float*)d_out;

  char* ws = (char*)d_ws;
  us* xb_hi  = (us*)(ws + 0);            // 4096x1024 (8 MB each)
  us* xb_lo  = (us*)(ws + 8388608);
  us* db_hi  = (us*)(ws + 16777216);
  us* db_lo  = (us*)(ws + 25165824);
  us* Wat_hi = (us*)(ws + 33554432);     // 3072x1024 (6 MB each)
  us* Wat_lo = (us*)(ws + 39845888);
  us* Wdt_hi = (us*)(ws + 46137344);     // 2048x1024 (4 MB each)
  us* Wdt_lo = (us*)(ws + 50331648);
  us* Wpt_hi = (us*)(ws + 54525952);     // 1024x1024 (2 MB each)
  us* Wpt_lo = (us*)(ws + 56623104);
  us* Qh     = (us*)(ws + 58720256);     // [2][2048][1024] (8 MB each)
  us* Ql     = (us*)(ws + 67108864);
  us* Kh     = (us*)(ws + 75497472);     // [2][4096][1024] (16 MB each)
  us* Kl     = (us*)(ws + 92274688);
  us* VT     = (us*)(ws + 109051904);    // [2][1024][4096] transposed V (16 MB)
  // regions dead by attn time, reused:
  us* attno  = (us*)(ws + 16777216);     // alias db_hi
  us* accP   = (us*)(ws + 33554432);     // alias Wat_* (+into Wdt_hi): 2 x 8 MB partial O
  float* Mv  = (float*)(ws + 50331648);  // alias Wdt_lo: 2 x 64K floats (512 KB)
  float* Lv  = (float*)(ws + 50855936);  //               2 x 64K floats (512 KB)

  split_cast_all<<<4096, 256, 0, stream>>>(x, data, xb_hi, xb_lo, db_hi, db_lo);
  transpose_all<<<dim3(192, 32), 256, 0, stream>>>(W_attn, W_data, W_proj,
                                                   Wat_hi, Wat_lo, Wdt_hi, Wdt_lo, Wpt_hi, Wpt_lo);

  gemm_all<<<dim3(40, 32), 256, 0, stream>>>(xb_hi, xb_lo, db_hi, db_lo,
                                             Wat_hi, Wat_lo, Wdt_hi, Wdt_lo,
                                             b_attn, b_data, Qh, Ql, Kh, Kl, VT);

  attn_kernel<<<1024, 256, 0, stream>>>(Qh, Ql, Kh, Kl, VT, accP, Mv, Lv);
  combine_kernel<<<2048, 256, 0, stream>>>(accP, Mv, Lv, attno);

  gemm_proj<<<dim3(8, 32), 256, 0, stream>>>(attno, Wpt_hi, b_proj, out);
}

// Round 9
// 306.779 us; speedup vs baseline: 1.4169x; 1.4169x over previous
//
#include <hip/hip_runtime.h>

typedef __bf16 bf16x8 __attribute__((ext_vector_type(8)));
typedef __bf16 bf16x4 __attribute__((ext_vector_type(4)));
typedef _Float16 f16x8 __attribute__((ext_vector_type(8)));
typedef float f32x4 __attribute__((ext_vector_type(4)));
typedef float f32x16 __attribute__((ext_vector_type(16)));
typedef unsigned short u16x8 __attribute__((ext_vector_type(8)));
typedef unsigned short u16x4 __attribute__((ext_vector_type(4)));
typedef unsigned int u32x4 __attribute__((ext_vector_type(4)));
typedef unsigned short us;

#define MM 2048
#define TT 4096

__device__ __forceinline__ us f2bf(float f){
  unsigned int u = __builtin_bit_cast(unsigned int, f);
  u = (u + 0x7fffu + ((u >> 16) & 1u)) >> 16;
  return (us)u;
}
__device__ __forceinline__ float bf2f(us u){
  unsigned int x = ((unsigned int)u) << 16;
  return __builtin_bit_cast(float, x);
}
__device__ __forceinline__ us f2h(float f){
  _Float16 h = (_Float16)f;
  return __builtin_bit_cast(us, h);
}
__device__ __forceinline__ unsigned int cvt_pk_bf16(float lo, float hi){
  unsigned int r;
  asm("v_cvt_pk_bf16_f32 %0, %1, %2" : "=v"(r) : "v"(lo), "v"(hi));
  return r;
}
__device__ __forceinline__ void plane_swap(unsigned int &x, unsigned int &y){
  asm("v_permlane32_swap_b32 %0, %1" : "+v"(x), "+v"(y));
}

#define GLDS(gp, lp) __builtin_amdgcn_global_load_lds( \
    (const __attribute__((address_space(1))) unsigned int*)(gp), \
    (__attribute__((address_space(3))) unsigned int*)(lp), 16, 0, 0)

// ---------------- fused fp32 -> bf16 hi/lo split (x and data in one launch) ----------------
__global__ __launch_bounds__(256) void split_cast_all(const float* __restrict__ x,
                                                      const float* __restrict__ data,
                                                      us* __restrict__ xh, us* __restrict__ xl,
                                                      us* __restrict__ dh, us* __restrict__ dl){
  int bid = blockIdx.x;
  const float* in; us* ho; us* lo;
  if (bid < 2048){ in = x; ho = xh; lo = xl; }
  else           { in = data; ho = dh; lo = dl; bid -= 2048; }
  size_t i = ((size_t)bid * 256 + threadIdx.x) * 8;
  float4 a = *(const float4*)(in + i);
  float4 b = *(const float4*)(in + i + 4);
  float v[8] = {a.x,a.y,a.z,a.w,b.x,b.y,b.z,b.w};
  u16x8 rh, rl;
  for (int j = 0; j < 8; j++){
    us h = f2bf(v[j]);
    rh[j] = h;
    rl[j] = f2bf(v[j] - bf2f(h));
  }
  *(u16x8*)(ho + i) = rh;
  *(u16x8*)(lo + i) = rl;
}

// ---------------- fused transpose + split for all three weights ----------------
__global__ __launch_bounds__(256) void transpose_all(const float* __restrict__ W_attn,
                                                     const float* __restrict__ W_data,
                                                     const float* __restrict__ W_proj,
                                                     us* __restrict__ Ah, us* __restrict__ Al,
                                                     us* __restrict__ Dh, us* __restrict__ Dl,
                                                     us* __restrict__ Ph, us* __restrict__ Pl2){
  __shared__ float tile[32][33];
  int bx = blockIdx.x;
  const float* W; us* oh; us* ol; int N;
  if (bx < 96){ W = W_attn; oh = Ah; ol = Al; N = 3072; }
  else if (bx < 160){ W = W_data; oh = Dh; ol = Dl; N = 2048; bx -= 96; }
  else { W = W_proj; oh = Ph; ol = Pl2; N = 1024; bx -= 160; }
  int tx = threadIdx.x & 31, ty = threadIdx.x >> 5;   // 32 x 8
  int n0 = bx * 32, k0 = blockIdx.y * 32;
  for (int r = 0; r < 32; r += 8)
    tile[ty + r][tx] = W[(size_t)(k0 + ty + r) * N + n0 + tx];
  __syncthreads();
  for (int r = 0; r < 32; r += 8){
    float v = tile[tx][ty + r];
    us h = f2bf(v);
    size_t idx = (size_t)(n0 + ty + r) * 1024 + k0 + tx;
    oh[idx] = h;
    ol[idx] = f2bf(v - bf2f(h));
  }
}

// ---------------- merged projection GEMM (q/k/v and k_data/v_data in one launch) ----------------
// bx<24: x @ W_attn (regions 0,1,2: Q,K,V, kroff 0). bx>=24: data @ W_data (regions 1,2, kroff 2048).
// Split regions (Q,K) use 3-MFMA hi/lo emulation for fp32 accuracy, then store FP16 single.
// V region stores bf16 transposed (VT[b][d][t]).
__global__ __launch_bounds__(256) void gemm_all(const us* __restrict__ xb_hi, const us* __restrict__ xb_lo,
                                                const us* __restrict__ db_hi, const us* __restrict__ db_lo,
                                                const us* __restrict__ Wat_hi, const us* __restrict__ Wat_lo,
                                                const us* __restrict__ Wdt_hi, const us* __restrict__ Wdt_lo,
                                                const float* __restrict__ b_attn, const float* __restrict__ b_data,
                                                us* __restrict__ Qf, us* __restrict__ Kf,
                                                us* __restrict__ VT){
  __shared__ us sm[16384];  // Ah@0, Bh@4096, Al@8192, Bl@12288
  const int bx = blockIdx.x;
  const us *Ah, *Al, *Bth, *Btl; const float* bias; int region, kroff, col0;
  if (bx < 24){
    Ah = xb_hi; Al = xb_lo; Bth = Wat_hi; Btl = Wat_lo; bias = b_attn;
    region = bx >> 3; kroff = 0; col0 = bx * 128;
  } else {
    int b2 = bx - 24;
    Ah = db_hi; Al = db_lo; Bth = Wdt_hi; Btl = Wdt_lo; bias = b_data;
    region = 1 + (b2 >> 3); kroff = 2048; col0 = b2 * 128;
  }
  const bool split = (region < 2);
  const int tid = threadIdx.x, wid = tid >> 6, lane = tid & 63;
  const int l15 = lane & 15, l16 = lane >> 4;
  const int row0 = blockIdx.y * 128;
  const int wr = (wid >> 1) * 64, wc = (wid & 1) * 64;
  f32x4 acc[4][4] = {};

  for (int k0 = 0; k0 < 1024; k0 += 32){
    for (int c = 0; c < 2; ++c){
      int i = c * 256 + tid;                           // 0..511: row=i>>2, k8=(i&3)*8
      size_t aoff = (size_t)(row0 + (i >> 2)) * 1024 + k0 + (i & 3) * 8;
      size_t boff = (size_t)(col0 + (i >> 2)) * 1024 + k0 + (i & 3) * 8;
      GLDS(Ah + aoff, &sm[c * 2048 + wid * 512]);
      GLDS(Bth + boff, &sm[4096 + c * 2048 + wid * 512]);
      if (split){
        GLDS(Al + aoff, &sm[8192 + c * 2048 + wid * 512]);
        GLDS(Btl + boff, &sm[12288 + c * 2048 + wid * 512]);
      }
    }
    __syncthreads();
    bf16x8 afh[4], bfh[4];
    for (int m = 0; m < 4; m++) afh[m] = *(const bf16x8*)&sm[(wr + m * 16 + l15) * 32 + l16 * 8];
    for (int n = 0; n < 4; n++) bfh[n] = *(const bf16x8*)&sm[4096 + (wc + n * 16 + l15) * 32 + l16 * 8];
    if (split){
      bf16x8 afl[4], bfl[4];
      for (int m = 0; m < 4; m++) afl[m] = *(const bf16x8*)&sm[8192 + (wr + m * 16 + l15) * 32 + l16 * 8];
      for (int n = 0; n < 4; n++) bfl[n] = *(const bf16x8*)&sm[12288 + (wc + n * 16 + l15) * 32 + l16 * 8];
      for (int m = 0; m < 4; m++)
        for (int n = 0; n < 4; n++){
          acc[m][n] = __builtin_amdgcn_mfma_f32_16x16x32_bf16(afh[m], bfh[n], acc[m][n], 0, 0, 0);
          acc[m][n] = __builtin_amdgcn_mfma_f32_16x16x32_bf16(afh[m], bfl[n], acc[m][n], 0, 0, 0);
          acc[m][n] = __builtin_amdgcn_mfma_f32_16x16x32_bf16(afl[m], bfh[n], acc[m][n], 0, 0, 0);
        }
    } else {
      for (int m = 0; m < 4; m++)
        for (int n = 0; n < 4; n++)
          acc[m][n] = __builtin_amdgcn_mfma_f32_16x16x32_bf16(afh[m], bfh[n], acc[m][n], 0, 0, 0);
    }
    __syncthreads();
  }

  for (int m = 0; m < 4; m++)
    for (int n = 0; n < 4; n++){
      int gcol = col0 + wc + n * 16 + l15;
      int ocol = gcol & 1023;
      float bv = bias[gcol];
      if (region == 2){                    // V -> VT[b][d][t] bf16, vectorized over 4 rows
        int r = row0 + wr + m * 16 + l16 * 4;
        u16x4 o;
        for (int j = 0; j < 4; j++) o[j] = f2bf(acc[m][n][j] + bv);
        *(u16x4*)&VT[((size_t)((r >> 11) * 1024 + ocol)) * 4096 + kroff + (r & 2047)] = o;
      } else {                             // Q or K -> fp16 single
        us* P = (region == 0) ? Qf : Kf;
        for (int j = 0; j < 4; j++){
          int r = row0 + wr + m * 16 + l16 * 4 + j;
          size_t orow = (region == 0) ? (size_t)r
                                      : (size_t)((r >> 11) * 4096 + kroff + (r & 2047));
          P[orow * 1024 + ocol] = f2h(acc[m][n][j] + bv);
        }
      }
    }
}

// ---------------- output projection GEMM (plain, fp32 out) ----------------
__global__ __launch_bounds__(256) void gemm_proj(const us* __restrict__ Ah,
                                                 const us* __restrict__ Bth,
                                                 const float* __restrict__ bias,
                                                 float* __restrict__ Co){
  __shared__ us sm[8192];
  const int tid = threadIdx.x, wid = tid >> 6, lane = tid & 63;
  const int l15 = lane & 15, l16 = lane >> 4;
  const int row0 = blockIdx.y * 128, col0 = blockIdx.x * 128;
  const int wr = (wid >> 1) * 64, wc = (wid & 1) * 64;
  f32x4 acc[4][4] = {};

  for (int k0 = 0; k0 < 1024; k0 += 32){
    for (int c = 0; c < 2; ++c){
      int i = c * 256 + tid;
      size_t aoff = (size_t)(row0 + (i >> 2)) * 1024 + k0 + (i & 3) * 8;
      size_t boff = (size_t)(col0 + (i >> 2)) * 1024 + k0 + (i & 3) * 8;
      GLDS(Ah + aoff, &sm[c * 2048 + wid * 512]);
      GLDS(Bth + boff, &sm[4096 + c * 2048 + wid * 512]);
    }
    __syncthreads();
    bf16x8 afh[4], bfh[4];
    for (int m = 0; m < 4; m++) afh[m] = *(const bf16x8*)&sm[(wr + m * 16 + l15) * 32 + l16 * 8];
    for (int n = 0; n < 4; n++) bfh[n] = *(const bf16x8*)&sm[4096 + (wc + n * 16 + l15) * 32 + l16 * 8];
    for (int m = 0; m < 4; m++)
      for (int n = 0; n < 4; n++)
        acc[m][n] = __builtin_amdgcn_mfma_f32_16x16x32_bf16(afh[m], bfh[n], acc[m][n], 0, 0, 0);
    __syncthreads();
  }

  for (int m = 0; m < 4; m++)
    for (int n = 0; n < 4; n++){
      int col = col0 + wc + n * 16 + l15;
      float bv = bias[col];
      for (int j = 0; j < 4; j++){
        int r = row0 + wr + m * 16 + l16 * 4 + j;
        Co[(size_t)r * 1024 + col] = acc[m][n][j] + bv;
      }
    }
}

// ---------------- fused attention: R7 structure, fp16 Q/K (single MFMA per frag) ----------------
// grid: B*H*(M/128); 4 waves x 32 q-rows. q = lane&31, hb = lane>>5.
// S^T C-layout (m74/m101): reg 4g+j -> t = ts*32 + 8g + 4*hb + j.
// K,V: LDS double-buffered, write-late + 1 barrier/tile. K fp16, V bf16.
// P: T12 cvt_pk + v_permlane32_swap (in-register, 0 bank conflicts). T13 defer-max.
__global__ __launch_bounds__(256) void attn_kernel(const us* __restrict__ Qf,
                                                   const us* __restrict__ Kf,
                                                   const us* __restrict__ VT,
                                                   us* __restrict__ attno){
  __shared__ us Kb[2][64 * 72];        // [dbuf][64 t][72] fp16
  __shared__ us Vb[2][64 * 72];        // [dbuf][64 d][72] bf16 (V^T tile)
  const int tid = threadIdx.x, wid = tid >> 6, lane = tid & 63;
  const int l31 = lane & 31, hb = lane >> 5, h8 = hb * 8;
  const int qt = blockIdx.x & 15;             // M/128 = 16
  const int bh = blockIdx.x >> 4;
  const int hd = (bh & 15) * 64, b = bh >> 4;
  const int qrow = qt * 128 + wid * 32 + l31;

  // Q fragments (B operand): lane holds Q[qrow][d = kk*16 + h8 + i], fp16
  f16x8 qf[4];
  {
    const us* qp = Qf + (size_t)(b * MM + qrow) * 1024 + hd;
#pragma unroll
    for (int kk = 0; kk < 4; kk++)
      qf[kk] = *(const f16x8*)(qp + kk * 16 + h8);
  }

  const int i0 = tid, i1 = 256 + tid;
  const int kt0 = i0 >> 3, kd0 = (i0 & 7) * 8;
  const int kt1 = i1 >> 3, kd1 = (i1 & 7) * 8;

#define GK(t0_, t_, d_) (((size_t)(b * TT + (t0_) + (t_))) * 1024 + hd + (d_))
#define GV(t0_, d_, t_) (((size_t)b * 1024 + hd + (d_)) * 4096 + (t0_) + (t_))

  // prologue: stage K,V tile 0 into buf 0
  uint4 rK0 = *(const uint4*)(Kf + GK(0, kt0, kd0));
  uint4 rK1 = *(const uint4*)(Kf + GK(0, kt1, kd1));
  uint4 rV0 = *(const uint4*)(VT + GV(0, kt0, kd0));
  uint4 rV1 = *(const uint4*)(VT + GV(0, kt1, kd1));
  *(uint4*)&Kb[0][kt0 * 72 + kd0] = rK0;
  *(uint4*)&Kb[0][kt1 * 72 + kd1] = rK1;
  *(uint4*)&Vb[0][kt0 * 72 + kd0] = rV0;
  *(uint4*)&Vb[0][kt1 * 72 + kd1] = rV1;
  __syncthreads();

  f32x16 acc0 = {}, acc1 = {};
  float mrow = -1e30f, lrow = 0.f;
  const float cs = 0.125f * 1.44269504088896f;   // to log2 domain

  for (int t0 = 0; t0 < TT; t0 += 64){
    const int cur = (t0 >> 6) & 1;
    const bool pre = (t0 + 64 < TT);
    if (pre){
      rK0 = *(const uint4*)(Kf + GK(t0 + 64, kt0, kd0));
      rK1 = *(const uint4*)(Kf + GK(t0 + 64, kt1, kd1));
      rV0 = *(const uint4*)(VT + GV(t0 + 64, kt0, kd0));
      rV1 = *(const uint4*)(VT + GV(t0 + 64, kt1, kd1));
    }

    // S^T = K . Q^T (fp16): frag ts holds t = ts*32 + tloc, q = l31
    const us* KbC = &Kb[cur][0];
    f32x16 sfr0 = {}, sfr1 = {};
    __builtin_amdgcn_s_setprio(1);
#pragma unroll
    for (int kk = 0; kk < 4; kk++){
      f16x8 a0 = *(const f16x8*)&KbC[l31 * 72 + kk * 16 + h8];
      f16x8 a1 = *(const f16x8*)&KbC[(32 + l31) * 72 + kk * 16 + h8];
      sfr0 = __builtin_amdgcn_mfma_f32_32x32x16_f16(a0, qf[kk], sfr0, 0, 0, 0);
      sfr1 = __builtin_amdgcn_mfma_f32_32x32x16_f16(a1, qf[kk], sfr1, 0, 0, 0);
    }
    __builtin_amdgcn_s_setprio(0);

    // online softmax (log2 domain, T13 defer-max, exp2 arg via fma fold)
    float v = -1e30f;
#pragma unroll
    for (int r = 0; r < 16; r++) v = fmaxf(v, fmaxf(sfr0[r], sfr1[r]));
    float vs = v * cs;
    vs = fmaxf(vs, __shfl_xor(vs, 32, 64));
    if (!__all(vs <= mrow + 8.f)){
      float mn = fmaxf(mrow, vs);
      float rs = __builtin_amdgcn_exp2f(mrow - mn);
      mrow = mn;
      lrow *= rs;
#pragma unroll
      for (int r = 0; r < 16; r++){ acc0[r] *= rs; acc1[r] *= rs; }
    }
    const float nm = -mrow;
    float tsum = 0.f;
    unsigned int A0[4][2], A1[4][2];
#pragma unroll
    for (int g = 0; g < 4; g++){
      float e00 = __builtin_amdgcn_exp2f(__builtin_fmaf(sfr0[4*g+0], cs, nm));
      float e01 = __builtin_amdgcn_exp2f(__builtin_fmaf(sfr0[4*g+1], cs, nm));
      float e02 = __builtin_amdgcn_exp2f(__builtin_fmaf(sfr0[4*g+2], cs, nm));
      float e03 = __builtin_amdgcn_exp2f(__builtin_fmaf(sfr0[4*g+3], cs, nm));
      float e10 = __builtin_amdgcn_exp2f(__builtin_fmaf(sfr1[4*g+0], cs, nm));
      float e11 = __builtin_amdgcn_exp2f(__builtin_fmaf(sfr1[4*g+1], cs, nm));
      float e12 = __builtin_amdgcn_exp2f(__builtin_fmaf(sfr1[4*g+2], cs, nm));
      float e13 = __builtin_amdgcn_exp2f(__builtin_fmaf(sfr1[4*g+3], cs, nm));
      tsum += (e00 + e01) + (e02 + e03) + (e10 + e11) + (e12 + e13);
      A0[g][0] = cvt_pk_bf16(e00, e01);
      A0[g][1] = cvt_pk_bf16(e02, e03);
      A1[g][0] = cvt_pk_bf16(e10, e11);
      A1[g][1] = cvt_pk_bf16(e12, e13);
    }
    tsum += __shfl_xor(tsum, 32, 64);
    lrow += tsum;

    // build P fragments in-register (T12): frag kk = {x'0, x'1, y'0, y'1}
    bf16x8 pf[4];
#pragma unroll
    for (int kkl = 0; kkl < 2; kkl++){
      unsigned int x0 = A0[2*kkl][0], y0 = A0[2*kkl+1][0];
      unsigned int x1 = A0[2*kkl][1], y1 = A0[2*kkl+1][1];
      plane_swap(x0, y0);
      plane_swap(x1, y1);
      u32x4 w = {x0, x1, y0, y1};
      pf[kkl] = __builtin_bit_cast(bf16x8, w);
      unsigned int z0 = A1[2*kkl][0], t0w = A1[2*kkl+1][0];
      unsigned int z1 = A1[2*kkl][1], t1w = A1[2*kkl+1][1];
      plane_swap(z0, t0w);
      plane_swap(z1, t1w);
      u32x4 w2 = {z0, z1, t0w, t1w};
      pf[2 + kkl] = __builtin_bit_cast(bf16x8, w2);
    }

    // O^T += V^T . P^T : A = V^T rows (LDS, shared), B = P (in-register)
    const us* VbC = &Vb[cur][0];
    __builtin_amdgcn_s_setprio(1);
#pragma unroll
    for (int kk = 0; kk < 4; kk++){
      bf16x8 av0 = *(const bf16x8*)&VbC[l31 * 72 + kk * 16 + h8];
      bf16x8 av1 = *(const bf16x8*)&VbC[(32 + l31) * 72 + kk * 16 + h8];
      acc0 = __builtin_amdgcn_mfma_f32_32x32x16_bf16(av0, pf[kk], acc0, 0, 0, 0);
      acc1 = __builtin_amdgcn_mfma_f32_32x32x16_bf16(av1, pf[kk], acc1, 0, 0, 0);
    }
    __builtin_amdgcn_s_setprio(0);

    // stage next tile into the other buffer, then single barrier
    if (pre){
      const int nxt = cur ^ 1;
      *(uint4*)&Kb[nxt][kt0 * 72 + kd0] = rK0;
      *(uint4*)&Kb[nxt][kt1 * 72 + kd1] = rK1;
      *(uint4*)&Vb[nxt][kt0 * 72 + kd0] = rV0;
      *(uint4*)&Vb[nxt][kt1 * 72 + kd1] = rV1;
    }
    __syncthreads();
  }
#undef GK
#undef GV

  float inv = 1.f / lrow;
  us* op = attno + (size_t)(b * MM + qrow) * 1024 + hd;
#pragma unroll
  for (int g = 0; g < 4; g++){
    bf16x4 w0, w1;
#pragma unroll
    for (int j = 0; j < 4; j++){
      w0[j] = (__bf16)(acc0[4 * g + j] * inv);
      w1[j] = (__bf16)(acc1[4 * g + j] * inv);
    }
    *(u16x4*)&op[8 * g + 4 * hb]      = __builtin_bit_cast(u16x4, w0);
    *(u16x4*)&op[32 + 8 * g + 4 * hb] = __builtin_bit_cast(u16x4, w1);
  }
}

extern "C" void kernel_launch(void* const* d_in, const int* in_sizes, int n_in,
                              void* d_out, int out_size, void* d_ws, size_t ws_size,
                              hipStream_t stream){
  const float* x      = (const float*)d_in[0];
  const float* data   = (const float*)d_in[1];
  const float* W_attn = (const float*)d_in[2];
  const float* b_attn = (const float*)d_in[3];
  const float* W_data = (const float*)d_in[4];
  const float* b_data = (const float*)d_in[5];
  const float* W_proj = (const float*)d_in[6];
  const float* b_proj = (const float*)d_in[7];
  float* out = (float*)d_out;

  char* ws = (char*)d_ws;
  us* xb_hi  = (us*)(ws + 0);            // 4096x1024 (8 MB each)
  us* xb_lo  = (us*)(ws + 8388608);
  us* db_hi  = (us*)(ws + 16777216);
  us* db_lo  = (us*)(ws + 25165824);
  us* Wat_hi = (us*)(ws + 33554432);     // 3072x1024 (6 MB each)
  us* Wat_lo = (us*)(ws + 39845888);
  us* Wdt_hi = (us*)(ws + 46137344);     // 2048x1024 (4 MB each)
  us* Wdt_lo = (us*)(ws + 50331648);
  us* Wpt_hi = (us*)(ws + 54525952);     // 1024x1024 (2 MB each)
  us* Wpt_lo = (us*)(ws + 56623104);
  us* Qf     = (us*)(ws + 58720256);     // [2][2048][1024] fp16 (8 MB)
  us* Kf     = (us*)(ws + 75497472);     // [2][4096][1024] fp16 (16 MB)
  us* VT     = (us*)(ws + 109051904);    // [2][1024][4096] transposed V bf16 (16 MB)
  us* attno  = (us*)(ws + 16777216);     // alias db_hi (db consumed before attn runs)

  split_cast_all<<<4096, 256, 0, stream>>>(x, data, xb_hi, xb_lo, db_hi, db_lo);
  transpose_all<<<dim3(192, 32), 256, 0, stream>>>(W_attn, W_data, W_proj,
                                                   Wat_hi, Wat_lo, Wdt_hi, Wdt_lo, Wpt_hi, Wpt_lo);

  gemm_all<<<dim3(40, 32), 256, 0, stream>>>(xb_hi, xb_lo, db_hi, db_lo,
                                             Wat_hi, Wat_lo, Wdt_hi, Wdt_lo,
                                             b_attn, b_data, Qf, Kf, VT);

  attn_kernel<<<512, 256, 0, stream>>>(Qf, Kf, VT, attno);

  gemm_proj<<<dim3(8, 32), 256, 0, stream>>>(attno, Wpt_hi, b_proj, out);
}

// Round 10
// 239.675 us; speedup vs baseline: 1.8136x; 1.2800x over previous
//
#include <hip/hip_runtime.h>

typedef __bf16 bf16x8 __attribute__((ext_vector_type(8)));
typedef __bf16 bf16x4 __attribute__((ext_vector_type(4)));
typedef _Float16 f16x8 __attribute__((ext_vector_type(8)));
typedef float f32x4 __attribute__((ext_vector_type(4)));
typedef float f32x16 __attribute__((ext_vector_type(16)));
typedef unsigned short u16x8 __attribute__((ext_vector_type(8)));
typedef unsigned short u16x4 __attribute__((ext_vector_type(4)));
typedef unsigned int u32x4 __attribute__((ext_vector_type(4)));
typedef unsigned short us;

#define MM 2048
#define TT 4096

__device__ __forceinline__ us f2bf(float f){
  unsigned int u = __builtin_bit_cast(unsigned int, f);
  u = (u + 0x7fffu + ((u >> 16) & 1u)) >> 16;
  return (us)u;
}
__device__ __forceinline__ float bf2f(us u){
  unsigned int x = ((unsigned int)u) << 16;
  return __builtin_bit_cast(float, x);
}
__device__ __forceinline__ us f2h(float f){
  _Float16 h = (_Float16)f;
  return __builtin_bit_cast(us, h);
}
__device__ __forceinline__ unsigned int cvt_pk_bf16(float lo, float hi){
  unsigned int r;
  asm("v_cvt_pk_bf16_f32 %0, %1, %2" : "=v"(r) : "v"(lo), "v"(hi));
  return r;
}
__device__ __forceinline__ void plane_swap(unsigned int &x, unsigned int &y){
  asm("v_permlane32_swap_b32 %0, %1" : "+v"(x), "+v"(y));
}

#define GLDS(gp, lp) __builtin_amdgcn_global_load_lds( \
    (const __attribute__((address_space(1))) unsigned int*)(gp), \
    (__attribute__((address_space(3))) unsigned int*)(lp), 16, 0, 0)

// ---------------- fused fp32 -> fp16 cast (x and data in one launch) ----------------
__global__ __launch_bounds__(256) void cast_f16_all(const float* __restrict__ x,
                                                    const float* __restrict__ data,
                                                    us* __restrict__ xf, us* __restrict__ df){
  int bid = blockIdx.x;
  const float* in; us* o;
  if (bid < 2048){ in = x; o = xf; }
  else           { in = data; o = df; bid -= 2048; }
  size_t i = ((size_t)bid * 256 + threadIdx.x) * 8;
  float4 a = *(const float4*)(in + i);
  float4 b = *(const float4*)(in + i + 4);
  float v[8] = {a.x,a.y,a.z,a.w,b.x,b.y,b.z,b.w};
  u16x8 r;
  for (int j = 0; j < 8; j++) r[j] = f2h(v[j]);
  *(u16x8*)(o + i) = r;
}

// ---------------- fused transpose for all three weights (attn/data fp16, proj bf16) ----------------
__global__ __launch_bounds__(256) void transpose_all(const float* __restrict__ W_attn,
                                                     const float* __restrict__ W_data,
                                                     const float* __restrict__ W_proj,
                                                     us* __restrict__ Af, us* __restrict__ Df,
                                                     us* __restrict__ Pb){
  __shared__ float tile[32][33];
  int bx = blockIdx.x;
  const float* W; us* o; int N; bool tobf;
  if (bx < 96){ W = W_attn; o = Af; N = 3072; tobf = false; }
  else if (bx < 160){ W = W_data; o = Df; N = 2048; bx -= 96; tobf = false; }
  else { W = W_proj; o = Pb; N = 1024; bx -= 160; tobf = true; }
  int tx = threadIdx.x & 31, ty = threadIdx.x >> 5;   // 32 x 8
  int n0 = bx * 32, k0 = blockIdx.y * 32;
  for (int r = 0; r < 32; r += 8)
    tile[ty + r][tx] = W[(size_t)(k0 + ty + r) * N + n0 + tx];
  __syncthreads();
  for (int r = 0; r < 32; r += 8){
    float v = tile[tx][ty + r];
    size_t idx = (size_t)(n0 + ty + r) * 1024 + k0 + tx;
    o[idx] = tobf ? f2bf(v) : f2h(v);
  }
}

// ---------------- merged projection GEMM, single-pass fp16 ----------------
// bx<24: xf @ Watf (regions 0,1,2: Q,K,V, kroff 0). bx>=24: df @ Wdtf (regions 1,2, kroff 2048).
// 128x128 tile, BK=32, 4 waves (2x2), 16x16x32 f16 MFMA (fp32 accum).
// Q -> Qf fp16 rows r; K -> Kf fp16 rows (r>>11)*4096+kroff+(r&2047); V -> VT bf16 [b][d][t].
__global__ __launch_bounds__(256) void gemm_all(const us* __restrict__ xf, const us* __restrict__ df,
                                                const us* __restrict__ Watf, const us* __restrict__ Wdtf,
                                                const float* __restrict__ b_attn, const float* __restrict__ b_data,
                                                us* __restrict__ Qf, us* __restrict__ Kf,
                                                us* __restrict__ VT){
  __shared__ us sm[8192];  // A@0, B@4096
  const int bx = blockIdx.x;
  const us *Ah, *Bth; const float* bias; int region, kroff, col0;
  if (bx < 24){
    Ah = xf; Bth = Watf; bias = b_attn;
    region = bx >> 3; kroff = 0; col0 = bx * 128;
  } else {
    int b2 = bx - 24;
    Ah = df; Bth = Wdtf; bias = b_data;
    region = 1 + (b2 >> 3); kroff = 2048; col0 = b2 * 128;
  }
  const int tid = threadIdx.x, wid = tid >> 6, lane = tid & 63;
  const int l15 = lane & 15, l16 = lane >> 4;
  const int row0 = blockIdx.y * 128;
  const int wr = (wid >> 1) * 64, wc = (wid & 1) * 64;
  f32x4 acc[4][4] = {};

  for (int k0 = 0; k0 < 1024; k0 += 32){
    for (int c = 0; c < 2; ++c){
      int i = c * 256 + tid;                           // 0..511: row=i>>2, k8=(i&3)*8
      size_t aoff = (size_t)(row0 + (i >> 2)) * 1024 + k0 + (i & 3) * 8;
      size_t boff = (size_t)(col0 + (i >> 2)) * 1024 + k0 + (i & 3) * 8;
      GLDS(Ah + aoff, &sm[c * 2048 + wid * 512]);
      GLDS(Bth + boff, &sm[4096 + c * 2048 + wid * 512]);
    }
    __syncthreads();
    f16x8 af[4], bf[4];
    for (int m = 0; m < 4; m++) af[m] = *(const f16x8*)&sm[(wr + m * 16 + l15) * 32 + l16 * 8];
    for (int n = 0; n < 4; n++) bf[n] = *(const f16x8*)&sm[4096 + (wc + n * 16 + l15) * 32 + l16 * 8];
    for (int m = 0; m < 4; m++)
      for (int n = 0; n < 4; n++)
        acc[m][n] = __builtin_amdgcn_mfma_f32_16x16x32_f16(af[m], bf[n], acc[m][n], 0, 0, 0);
    __syncthreads();
  }

  for (int m = 0; m < 4; m++)
    for (int n = 0; n < 4; n++){
      int gcol = col0 + wc + n * 16 + l15;
      int ocol = gcol & 1023;
      float bv = bias[gcol];
      if (region == 2){                    // V -> VT[b][d][t] bf16, vectorized over 4 rows
        int r = row0 + wr + m * 16 + l16 * 4;
        u16x4 o;
        for (int j = 0; j < 4; j++) o[j] = f2bf(acc[m][n][j] + bv);
        *(u16x4*)&VT[((size_t)((r >> 11) * 1024 + ocol)) * 4096 + kroff + (r & 2047)] = o;
      } else {                             // Q or K -> fp16
        us* P = (region == 0) ? Qf : Kf;
        for (int j = 0; j < 4; j++){
          int r = row0 + wr + m * 16 + l16 * 4 + j;
          size_t orow = (region == 0) ? (size_t)r
                                      : (size_t)((r >> 11) * 4096 + kroff + (r & 2047));
          P[orow * 1024 + ocol] = f2h(acc[m][n][j] + bv);
        }
      }
    }
}

// ---------------- output projection GEMM (bf16, fp32 out) ----------------
__global__ __launch_bounds__(256) void gemm_proj(const us* __restrict__ Ah,
                                                 const us* __restrict__ Bth,
                                                 const float* __restrict__ bias,
                                                 float* __restrict__ Co){
  __shared__ us sm[8192];
  const int tid = threadIdx.x, wid = tid >> 6, lane = tid & 63;
  const int l15 = lane & 15, l16 = lane >> 4;
  const int row0 = blockIdx.y * 128, col0 = blockIdx.x * 128;
  const int wr = (wid >> 1) * 64, wc = (wid & 1) * 64;
  f32x4 acc[4][4] = {};

  for (int k0 = 0; k0 < 1024; k0 += 32){
    for (int c = 0; c < 2; ++c){
      int i = c * 256 + tid;
      size_t aoff = (size_t)(row0 + (i >> 2)) * 1024 + k0 + (i & 3) * 8;
      size_t boff = (size_t)(col0 + (i >> 2)) * 1024 + k0 + (i & 3) * 8;
      GLDS(Ah + aoff, &sm[c * 2048 + wid * 512]);
      GLDS(Bth + boff, &sm[4096 + c * 2048 + wid * 512]);
    }
    __syncthreads();
    bf16x8 afh[4], bfh[4];
    for (int m = 0; m < 4; m++) afh[m] = *(const bf16x8*)&sm[(wr + m * 16 + l15) * 32 + l16 * 8];
    for (int n = 0; n < 4; n++) bfh[n] = *(const bf16x8*)&sm[4096 + (wc + n * 16 + l15) * 32 + l16 * 8];
    for (int m = 0; m < 4; m++)
      for (int n = 0; n < 4; n++)
        acc[m][n] = __builtin_amdgcn_mfma_f32_16x16x32_bf16(afh[m], bfh[n], acc[m][n], 0, 0, 0);
    __syncthreads();
  }

  for (int m = 0; m < 4; m++)
    for (int n = 0; n < 4; n++){
      int col = col0 + wc + n * 16 + l15;
      float bv = bias[col];
      for (int j = 0; j < 4; j++){
        int r = row0 + wr + m * 16 + l16 * 4 + j;
        Co[(size_t)r * 1024 + col] = acc[m][n][j] + bv;
      }
    }
}

// ---------------- fused attention: R9 structure (fp16 Q/K, bf16 V) ----------------
// grid: B*H*(M/128); 4 waves x 32 q-rows. q = lane&31, hb = lane>>5.
// S^T C-layout (m74/m101): reg 4g+j -> t = ts*32 + 8g + 4*hb + j.
// K,V: LDS double-buffered, write-late + 1 barrier/tile.
// P: T12 cvt_pk + v_permlane32_swap (in-register, 0 bank conflicts). T13 defer-max.
__global__ __launch_bounds__(256) void attn_kernel(const us* __restrict__ Qf,
                                                   const us* __restrict__ Kf,
                                                   const us* __restrict__ VT,
                                                   us* __restrict__ attno){
  __shared__ us Kb[2][64 * 72];        // [dbuf][64 t][72] fp16
  __shared__ us Vb[2][64 * 72];        // [dbuf][64 d][72] bf16 (V^T tile)
  const int tid = threadIdx.x, wid = tid >> 6, lane = tid & 63;
  const int l31 = lane & 31, hb = lane >> 5, h8 = hb * 8;
  const int qt = blockIdx.x & 15;             // M/128 = 16
  const int bh = blockIdx.x >> 4;
  const int hd = (bh & 15) * 64, b = bh >> 4;
  const int qrow = qt * 128 + wid * 32 + l31;

  // Q fragments (B operand): lane holds Q[qrow][d = kk*16 + h8 + i], fp16
  f16x8 qf[4];
  {
    const us* qp = Qf + (size_t)(b * MM + qrow) * 1024 + hd;
#pragma unroll
    for (int kk = 0; kk < 4; kk++)
      qf[kk] = *(const f16x8*)(qp + kk * 16 + h8);
  }

  const int i0 = tid, i1 = 256 + tid;
  const int kt0 = i0 >> 3, kd0 = (i0 & 7) * 8;
  const int kt1 = i1 >> 3, kd1 = (i1 & 7) * 8;

#define GK(t0_, t_, d_) (((size_t)(b * TT + (t0_) + (t_))) * 1024 + hd + (d_))
#define GV(t0_, d_, t_) (((size_t)b * 1024 + hd + (d_)) * 4096 + (t0_) + (t_))

  // prologue: stage K,V tile 0 into buf 0
  uint4 rK0 = *(const uint4*)(Kf + GK(0, kt0, kd0));
  uint4 rK1 = *(const uint4*)(Kf + GK(0, kt1, kd1));
  uint4 rV0 = *(const uint4*)(VT + GV(0, kt0, kd0));
  uint4 rV1 = *(const uint4*)(VT + GV(0, kt1, kd1));
  *(uint4*)&Kb[0][kt0 * 72 + kd0] = rK0;
  *(uint4*)&Kb[0][kt1 * 72 + kd1] = rK1;
  *(uint4*)&Vb[0][kt0 * 72 + kd0] = rV0;
  *(uint4*)&Vb[0][kt1 * 72 + kd1] = rV1;
  __syncthreads();

  f32x16 acc0 = {}, acc1 = {};
  float mrow = -1e30f, lrow = 0.f;
  const float cs = 0.125f * 1.44269504088896f;   // to log2 domain

  for (int t0 = 0; t0 < TT; t0 += 64){
    const int cur = (t0 >> 6) & 1;
    const bool pre = (t0 + 64 < TT);
    if (pre){
      rK0 = *(const uint4*)(Kf + GK(t0 + 64, kt0, kd0));
      rK1 = *(const uint4*)(Kf + GK(t0 + 64, kt1, kd1));
      rV0 = *(const uint4*)(VT + GV(t0 + 64, kt0, kd0));
      rV1 = *(const uint4*)(VT + GV(t0 + 64, kt1, kd1));
    }

    // S^T = K . Q^T (fp16): frag ts holds t = ts*32 + tloc, q = l31
    const us* KbC = &Kb[cur][0];
    f32x16 sfr0 = {}, sfr1 = {};
    __builtin_amdgcn_s_setprio(1);
#pragma unroll
    for (int kk = 0; kk < 4; kk++){
      f16x8 a0 = *(const f16x8*)&KbC[l31 * 72 + kk * 16 + h8];
      f16x8 a1 = *(const f16x8*)&KbC[(32 + l31) * 72 + kk * 16 + h8];
      sfr0 = __builtin_amdgcn_mfma_f32_32x32x16_f16(a0, qf[kk], sfr0, 0, 0, 0);
      sfr1 = __builtin_amdgcn_mfma_f32_32x32x16_f16(a1, qf[kk], sfr1, 0, 0, 0);
    }
    __builtin_amdgcn_s_setprio(0);

    // online softmax (log2 domain, T13 defer-max, exp2 arg via fma fold)
    float v = -1e30f;
#pragma unroll
    for (int r = 0; r < 16; r++) v = fmaxf(v, fmaxf(sfr0[r], sfr1[r]));
    float vs = v * cs;
    vs = fmaxf(vs, __shfl_xor(vs, 32, 64));
    if (!__all(vs <= mrow + 8.f)){
      float mn = fmaxf(mrow, vs);
      float rs = __builtin_amdgcn_exp2f(mrow - mn);
      mrow = mn;
      lrow *= rs;
#pragma unroll
      for (int r = 0; r < 16; r++){ acc0[r] *= rs; acc1[r] *= rs; }
    }
    const float nm = -mrow;
    float tsum = 0.f;
    unsigned int A0[4][2], A1[4][2];
#pragma unroll
    for (int g = 0; g < 4; g++){
      float e00 = __builtin_amdgcn_exp2f(__builtin_fmaf(sfr0[4*g+0], cs, nm));
      float e01 = __builtin_amdgcn_exp2f(__builtin_fmaf(sfr0[4*g+1], cs, nm));
      float e02 = __builtin_amdgcn_exp2f(__builtin_fmaf(sfr0[4*g+2], cs, nm));
      float e03 = __builtin_amdgcn_exp2f(__builtin_fmaf(sfr0[4*g+3], cs, nm));
      float e10 = __builtin_amdgcn_exp2f(__builtin_fmaf(sfr1[4*g+0], cs, nm));
      float e11 = __builtin_amdgcn_exp2f(__builtin_fmaf(sfr1[4*g+1], cs, nm));
      float e12 = __builtin_amdgcn_exp2f(__builtin_fmaf(sfr1[4*g+2], cs, nm));
      float e13 = __builtin_amdgcn_exp2f(__builtin_fmaf(sfr1[4*g+3], cs, nm));
      tsum += (e00 + e01) + (e02 + e03) + (e10 + e11) + (e12 + e13);
      A0[g][0] = cvt_pk_bf16(e00, e01);
      A0[g][1] = cvt_pk_bf16(e02, e03);
      A1[g][0] = cvt_pk_bf16(e10, e11);
      A1[g][1] = cvt_pk_bf16(e12, e13);
    }
    tsum += __shfl_xor(tsum, 32, 64);
    lrow += tsum;

    // build P fragments in-register (T12): frag kk = {x'0, x'1, y'0, y'1}
    bf16x8 pf[4];
#pragma unroll
    for (int kkl = 0; kkl < 2; kkl++){
      unsigned int x0 = A0[2*kkl][0], y0 = A0[2*kkl+1][0];
      unsigned int x1 = A0[2*kkl][1], y1 = A0[2*kkl+1][1];
      plane_swap(x0, y0);
      plane_swap(x1, y1);
      u32x4 w = {x0, x1, y0, y1};
      pf[kkl] = __builtin_bit_cast(bf16x8, w);
      unsigned int z0 = A1[2*kkl][0], t0w = A1[2*kkl+1][0];
      unsigned int z1 = A1[2*kkl][1], t1w = A1[2*kkl+1][1];
      plane_swap(z0, t0w);
      plane_swap(z1, t1w);
      u32x4 w2 = {z0, z1, t0w, t1w};
      pf[2 + kkl] = __builtin_bit_cast(bf16x8, w2);
    }

    // O^T += V^T . P^T : A = V^T rows (LDS, shared), B = P (in-register)
    const us* VbC = &Vb[cur][0];
    __builtin_amdgcn_s_setprio(1);
#pragma unroll
    for (int kk = 0; kk < 4; kk++){
      bf16x8 av0 = *(const bf16x8*)&VbC[l31 * 72 + kk * 16 + h8];
      bf16x8 av1 = *(const bf16x8*)&VbC[(32 + l31) * 72 + kk * 16 + h8];
      acc0 = __builtin_amdgcn_mfma_f32_32x32x16_bf16(av0, pf[kk], acc0, 0, 0, 0);
      acc1 = __builtin_amdgcn_mfma_f32_32x32x16_bf16(av1, pf[kk], acc1, 0, 0, 0);
    }
    __builtin_amdgcn_s_setprio(0);

    // stage next tile into the other buffer, then single barrier
    if (pre){
      const int nxt = cur ^ 1;
      *(uint4*)&Kb[nxt][kt0 * 72 + kd0] = rK0;
      *(uint4*)&Kb[nxt][kt1 * 72 + kd1] = rK1;
      *(uint4*)&Vb[nxt][kt0 * 72 + kd0] = rV0;
      *(uint4*)&Vb[nxt][kt1 * 72 + kd1] = rV1;
    }
    __syncthreads();
  }
#undef GK
#undef GV

  float inv = 1.f / lrow;
  us* op = attno + (size_t)(b * MM + qrow) * 1024 + hd;
#pragma unroll
  for (int g = 0; g < 4; g++){
    bf16x4 w0, w1;
#pragma unroll
    for (int j = 0; j < 4; j++){
      w0[j] = (__bf16)(acc0[4 * g + j] * inv);
      w1[j] = (__bf16)(acc1[4 * g + j] * inv);
    }
    *(u16x4*)&op[8 * g + 4 * hb]      = __builtin_bit_cast(u16x4, w0);
    *(u16x4*)&op[32 + 8 * g + 4 * hb] = __builtin_bit_cast(u16x4, w1);
  }
}

extern "C" void kernel_launch(void* const* d_in, const int* in_sizes, int n_in,
                              void* d_out, int out_size, void* d_ws, size_t ws_size,
                              hipStream_t stream){
  const float* x      = (const float*)d_in[0];
  const float* data   = (const float*)d_in[1];
  const float* W_attn = (const float*)d_in[2];
  const float* b_attn = (const float*)d_in[3];
  const float* W_data = (const float*)d_in[4];
  const float* b_data = (const float*)d_in[5];
  const float* W_proj = (const float*)d_in[6];
  const float* b_proj = (const float*)d_in[7];
  float* out = (float*)d_out;

  char* ws = (char*)d_ws;
  us* xf    = (us*)(ws + 0);             // [2][2048][1024] fp16 (8 MB)
  us* df    = (us*)(ws + 8388608);       // [2][2048][1024] fp16 (8 MB)
  us* Watf  = (us*)(ws + 16777216);      // [3072][1024] fp16 (6 MB)
  us* Wdtf  = (us*)(ws + 23068672);      // [2048][1024] fp16 (4 MB)
  us* Wptb  = (us*)(ws + 27262976);      // [1024][1024] bf16 (2 MB)
  us* Qf    = (us*)(ws + 29360128);      // [2][2048][1024] fp16 (8 MB)
  us* Kf    = (us*)(ws + 37748736);      // [2][4096][1024] fp16 (16 MB)
  us* VT    = (us*)(ws + 54525952);      // [2][1024][4096] bf16 (16 MB)
  us* attno = (us*)(ws + 0);             // alias xf (dead after gemm_all)

  cast_f16_all<<<4096, 256, 0, stream>>>(x, data, xf, df);
  transpose_all<<<dim3(192, 32), 256, 0, stream>>>(W_attn, W_data, W_proj, Watf, Wdtf, Wptb);

  gemm_all<<<dim3(40, 32), 256, 0, stream>>>(xf, df, Watf, Wdtf,
                                             b_attn, b_data, Qf, Kf, VT);

  attn_kernel<<<512, 256, 0, stream>>>(Qf, Kf, VT, attno);

  gemm_proj<<<dim3(8, 32), 256, 0, stream>>>(attno, Wptb, b_proj, out);
}